// Round 3
// baseline (125.130 us; speedup 1.0000x reference)
//
#include <hip/hip_runtime.h>

#define NF 160
#define NP 80
#define ND 64
#define NC 512
#define NV 81                  // stored v columns 0..80 (Hermitian half)
#define NPIXH (NF*NV)          // 12960
#define NPIXP 13056            // padded to 51*256
#define NXBLK 51
#define NJ NXBLK               // partial rows = blocks (reduced in-block)
#define CPB 16                 // candidates per block
#define TWO_PI 6.283185307179586f

// per-pixel precomputed parameter slots
#define IP_AR 0
#define IP_AI 1
#define IP_BR 2
#define IP_BI 3
#define IP_P  4
#define IP_Q  5
#define IP_R  6
#define IP_C2T 7
#define IP_S2T 8
#define IP_K  9
#define IP_CD0 10
#define IP_SD0 11
#define IP_CD1 12
#define IP_SD1 13
#define IP_TCD 14
#define IP_S0 15
#define IP_W  16
#define NPRM 17

__device__ __forceinline__ void rot(float& c, float& s, float stc, float sts) {
  float t1 = s * sts;
  float t2 = s * stc;
  float cn = fmaf(c, stc, -t1);
  s = fmaf(c, sts, t2);
  c = cn;
}

__device__ __forceinline__ void start_i_pow(int n, float& c, float& s) {
  switch (n & 3) {
    case 0: c = 1.f; s = 0.f; break;
    case 1: c = 0.f; s = 1.f; break;
    case 2: c = -1.f; s = 0.f; break;
    default: c = 0.f; s = -1.f; break;
  }
}

// Pass 1: T[d][a][v] = sum_b yw[d,a,b] * e^{-2pi i v (b-40)/160}, v in 0..80
__global__ __launch_bounds__(256) void k_fft_x(const float* __restrict__ patch,
                                               const float* __restrict__ gw,
                                               float2* __restrict__ T) {
  int idx = blockIdx.x * 256 + threadIdx.x;   // ND*NP*NV = 414720
  int v = idx % NV;
  int a = (idx / NV) % NP;
  int d = idx / (NV * NP);
  float c, s;
  start_i_pow(v, c, s);
  float stc, sts;
  sincosf(-TWO_PI * (float)v / (float)NF, &sts, &stc);
  const float* prow = patch + (size_t)(d * NP + a) * NP;
  const float* grow = gw + a * NP;
  float accR = 0.f, accI = 0.f;
  for (int b = 0; b < NP; ++b) {
    float f = prow[b] * grow[b];
    accR = fmaf(f, c, accR);
    accI = fmaf(f, s, accI);
    rot(c, s, stc, sts);
  }
  T[idx] = make_float2(accR, accI);
}

// Pass 2: Y[d][u][v] = sum_a T[d][a][v] * e^{-2pi i u (a-40)/160}
__global__ __launch_bounds__(256) void k_fft_y(const float2* __restrict__ T,
                                               float2* __restrict__ Y) {
  int idx = blockIdx.x * 256 + threadIdx.x;   // 64*40*81 = 207360
  int v = idx % NV;
  int ug = (idx / NV) % 40;
  int d = idx / (NV * 40);
  float c[4], s[4], aR[4], aI[4], stc[4], sts[4];
#pragma unroll
  for (int j = 0; j < 4; ++j) {
    int u = ug * 4 + j;
    start_i_pow(u, c[j], s[j]);
    sincosf(-TWO_PI * (float)u / (float)NF, &sts[j], &stc[j]);
    aR[j] = 0.f; aI[j] = 0.f;
  }
  const float2* Tb = T + (size_t)(d * NP) * NV + v;
  for (int a = 0; a < NP; ++a) {
    float2 t = Tb[(size_t)a * NV];
#pragma unroll
    for (int j = 0; j < 4; ++j) {
      aR[j] = fmaf(t.x, c[j], aR[j]);
      aR[j] = fmaf(-t.y, s[j], aR[j]);
      aI[j] = fmaf(t.x, s[j], aI[j]);
      aI[j] = fmaf(t.y, c[j], aI[j]);
      rot(c[j], s[j], stc[j], sts[j]);
    }
  }
#pragma unroll
  for (int j = 0; j < 4; ++j) {
    int u = ug * 4 + j;
    Y[((size_t)d * NF + u) * NV + v] = make_float2(aR[j], aI[j]);
  }
}

// Per-pixel candidate-independent moments over half-plane (padded).
// Yk2[j][p] = (yk[j], yk[63-j]) pairs for the dual Chebyshev chains.
__global__ __launch_bounds__(256) void k_prep(const float2* __restrict__ Y,
                                              const float* __restrict__ delays,
                                              const float* __restrict__ kloss,
                                              const float* __restrict__ theta,
                                              float2* __restrict__ Yk2,
                                              float* __restrict__ prm) {
  int p = blockIdx.x * 256 + threadIdx.x;     // 51*256 = 13056
  if (p >= NPIXH) {
    for (int j = 0; j < ND / 2; ++j) Yk2[(size_t)j * NPIXP + p] = make_float2(0.f, 0.f);
    prm[IP_AR * NPIXP + p] = 0.f;  prm[IP_AI * NPIXP + p] = 0.f;
    prm[IP_BR * NPIXP + p] = 0.f;  prm[IP_BI * NPIXP + p] = 0.f;
    prm[IP_P * NPIXP + p] = 1.f;   prm[IP_Q * NPIXP + p] = 0.f;
    prm[IP_R * NPIXP + p] = 1.f;   prm[IP_C2T * NPIXP + p] = 0.f;
    prm[IP_S2T * NPIXP + p] = 0.f; prm[IP_K * NPIXP + p] = 0.f;
    prm[IP_CD0 * NPIXP + p] = 1.f; prm[IP_SD0 * NPIXP + p] = 0.f;
    prm[IP_CD1 * NPIXP + p] = 1.f; prm[IP_SD1 * NPIXP + p] = 0.f;
    prm[IP_TCD * NPIXP + p] = 2.f; prm[IP_S0 * NPIXP + p] = 0.f;
    prm[IP_W * NPIXP + p] = 0.f;
    return;
  }
  int u = p / NV, v = p % NV;
  float k = kloss[u * NF + v];
  float th = theta[((u + 80) % NF) * NF + ((v + 80) % NF)];
  float c2t = cosf(2.f * th), s2t = sinf(2.f * th);
  float w;
  if (v == 0 || v == 80) {
    if (u == 0 || u == 80) w = 1.f;
    else if (u < 80) w = 2.f;
    else w = 0.f;
  } else w = 2.f;
  float d0 = delays[0], d1 = delays[1];
  float sd0f, cd0f;
  sincosf(k * d0, &sd0f, &cd0f);
  float stc, sts;
  sincosf(k * (d1 - d0), &sts, &stc);
  float tcd = 2.f * stc;
  float cd = cd0f, sd = sd0f;
  float cd1s = 0.f, sd1s = 0.f;
  float Ar = 0.f, Ai = 0.f, Br = 0.f, Bi = 0.f, Pm = 0.f, Qm = 0.f, Rm = 0.f, S0 = 0.f;
  float yktmp[ND];
  for (int d = 0; d < ND; ++d) {
    if (d == 1) { cd1s = cd; sd1s = sd; }
    float2 y = Y[((size_t)d * NF + u) * NV + v];
    Ar = fmaf(y.x, cd, Ar);  Ai = fmaf(y.y, cd, Ai);
    Br = fmaf(y.x, sd, Br);  Bi = fmaf(y.y, sd, Bi);
    Pm = fmaf(cd, cd, Pm);  Qm = fmaf(cd, sd, Qm);  Rm = fmaf(sd, sd, Rm);
    float yk = sqrtf(fmaf(y.x, y.x, y.y * y.y)) * k;
    yktmp[d] = yk;
    S0 = fmaf(yk, yk, S0);
    rot(cd, sd, stc, sts);
  }
#pragma unroll
  for (int j = 0; j < ND / 2; ++j)
    Yk2[(size_t)j * NPIXP + p] = make_float2(yktmp[j], yktmp[ND - 1 - j]);
  prm[IP_AR * NPIXP + p] = Ar;   prm[IP_AI * NPIXP + p] = Ai;
  prm[IP_BR * NPIXP + p] = Br;   prm[IP_BI * NPIXP + p] = Bi;
  prm[IP_P * NPIXP + p] = Pm;    prm[IP_Q * NPIXP + p] = Qm;
  prm[IP_R * NPIXP + p] = Rm;    prm[IP_C2T * NPIXP + p] = c2t;
  prm[IP_S2T * NPIXP + p] = s2t; prm[IP_K * NPIXP + p] = k;
  prm[IP_CD0 * NPIXP + p] = cd0f; prm[IP_SD0 * NPIXP + p] = sd0f;
  prm[IP_CD1 * NPIXP + p] = cd1s; prm[IP_SD1 * NPIXP + p] = sd1s;
  prm[IP_TCD * NPIXP + p] = tcd; prm[IP_S0 * NPIXP + p] = S0;
  prm[IP_W * NPIXP + p] = w;
}

// Hot kernel: per (pixel, candidate) loss via dual Chebyshev chains
// A_j = cos(k d_j - kw), B_j = cos(k d_j + kw), j = 0..31; d_{63-j} = -d_j.
__global__ __launch_bounds__(256, 4) void k_cand(const float2* __restrict__ Yk2,
                                                 const float* __restrict__ prm,
                                                 const float* __restrict__ cand,
                                                 float* __restrict__ partial) {
  int p = blockIdx.x * 256 + threadIdx.x;     // NXBLK=51 blocks in x
  int c0 = blockIdx.y * CPB;
  float Ar = prm[IP_AR * NPIXP + p], Ai = prm[IP_AI * NPIXP + p];
  float Br = prm[IP_BR * NPIXP + p], Bi = prm[IP_BI * NPIXP + p];
  float Pm = prm[IP_P * NPIXP + p], Qm = prm[IP_Q * NPIXP + p], Rm = prm[IP_R * NPIXP + p];
  float c2t = prm[IP_C2T * NPIXP + p], s2t = prm[IP_S2T * NPIXP + p];
  float k = prm[IP_K * NPIXP + p];
  float cd0 = prm[IP_CD0 * NPIXP + p], sd0 = prm[IP_SD0 * NPIXP + p];
  float cd1 = prm[IP_CD1 * NPIXP + p], sd1 = prm[IP_SD1 * NPIXP + p];
  float tcd = prm[IP_TCD * NPIXP + p], S0 = prm[IP_S0 * NPIXP + p];
  float wgt = prm[IP_W * NPIXP + p];
  float2 yk[ND / 2];
#pragma unroll
  for (int j = 0; j < ND / 2; ++j) yk[j] = Yk2[(size_t)j * NPIXP + p];
  int wid = threadIdx.x >> 6;
  int lane = threadIdx.x & 63;
  __shared__ float sdata[CPB][4];
  for (int ci = 0; ci < CPB; ++ci) {
    int c = c0 + ci;
    float dc = cand[c * 3 + 0], xx = cand[c * 3 + 1], yy = cand[c * 3 + 2];
    float w_ = fmaf(xx, c2t, fmaf(yy, s2t, dc));
    float kw = k * w_;
    float sw, cw;
    __sincosf(kw, &sw, &cw);
    float rr = fmaf(cw, Ar, sw * Br);
    float ri = fmaf(cw, Ai, sw * Bi);
    float lhs = fmaf(cw * cw, Pm, fmaf(2.f * cw * sw, Qm, sw * sw * Rm));
    float rabs = __builtin_amdgcn_sqrtf(fmaf(rr, rr, ri * ri));
    float rl = __builtin_amdgcn_rcpf(lhs);
    float e = fmaf(-lhs, rl, 1.f);
    rl = fmaf(rl, e, rl);                     // refined 1/lhs
    float kX = k * rabs * rl;
    // chain inits: cos(a -/+ b) = ca*cb +/- sa*sb
    float t0 = cd0 * cw, u0 = sd0 * sw;
    float t1 = cd1 * cw, u1 = sd1 * sw;
    float Am1 = t0 + u0, Bm1 = t0 - u0;       // A_0, B_0
    float Ac  = t1 + u1, Bc  = t1 - u1;       // A_1, B_1
    float MA0 = yk[0].x * fabsf(Am1);
    float MA1 = yk[1].x * fabsf(Ac);
    float MB0 = yk[0].y * fabsf(Bm1);
    float MB1 = yk[1].y * fabsf(Bc);
#pragma unroll
    for (int j = 2; j < ND / 2; j += 2) {
      float An = fmaf(tcd, Ac, -Am1);
      float Bn = fmaf(tcd, Bc, -Bm1);
      MA0 = fmaf(yk[j].x, fabsf(An), MA0);
      MB0 = fmaf(yk[j].y, fabsf(Bn), MB0);
      float An2 = fmaf(tcd, An, -Ac);
      float Bn2 = fmaf(tcd, Bn, -Bc);
      MA1 = fmaf(yk[j + 1].x, fabsf(An2), MA1);
      MB1 = fmaf(yk[j + 1].y, fabsf(Bn2), MB1);
      Am1 = An; Ac = An2;
      Bm1 = Bn; Bc = Bn2;
    }
    float M = (MA0 + MA1) + (MB0 + MB1);
    float contrib = fmaf(kX * kX, lhs, fmaf(-2.f * kX, M, S0)) * wgt;
    for (int off = 32; off > 0; off >>= 1) contrib += __shfl_xor(contrib, off);
    if (lane == 0) sdata[ci][wid] = contrib;
  }
  __syncthreads();
  if (threadIdx.x < CPB) {
    int ci = threadIdx.x;
    float s = (sdata[ci][0] + sdata[ci][1]) + (sdata[ci][2] + sdata[ci][3]);
    partial[(size_t)blockIdx.x * NC + c0 + ci] = s;
  }
}

__global__ void k_argmin(const float* __restrict__ partial,
                         const float* __restrict__ cand,
                         float* __restrict__ out, int* __restrict__ bestIdx) {
  __shared__ float sl[NC];
  __shared__ int si[NC];
  int c = threadIdx.x;                        // 512 threads
  float s = 0.f;
  for (int j = 0; j < NJ; ++j) s += partial[(size_t)j * NC + c];
  sl[c] = s * (1.f / 1638400.f);
  si[c] = c;
  __syncthreads();
  for (int off = 256; off > 0; off >>= 1) {
    if (c < off) {
      float l2 = sl[c + off]; int i2 = si[c + off];
      if (l2 < sl[c] || (l2 == sl[c] && i2 < si[c])) { sl[c] = l2; si[c] = i2; }
    }
    __syncthreads();
  }
  if (c == 0) {
    int bi = si[0];
    out[6400] = cand[bi * 3 + 0];
    out[6401] = cand[bi * 3 + 1];
    out[6402] = cand[bi * 3 + 2];
    out[6403] = sl[0];
    *bestIdx = bi;
  }
}

// Fused: expand best X (Hermitian) for row u into LDS, then row-DFT:
// G[u][b] = sum_v X[u,v] e^{+2pi i xb v/160}, xb=(b+120)%160
__global__ __launch_bounds__(256) void k_ifft_u(const float* __restrict__ prm,
                                                const float* __restrict__ cand,
                                                const int* __restrict__ bestIdx,
                                                float2* __restrict__ G) {
  int u = blockIdx.x;                         // 0..159
  __shared__ float xr[NF], xi[NF];
  int bi = *bestIdx;
  float dc = cand[bi * 3 + 0], xx = cand[bi * 3 + 1], yy = cand[bi * 3 + 2];
  int v = threadIdx.x;
  if (v < NF) {
    float sign = 1.f;
    int ph;
    if (v <= 80) {
      ph = u * NV + v;
    } else {
      int u2 = (NF - u) % NF;
      ph = u2 * NV + (NF - v);
      sign = -1.f;
    }
    float Ar = prm[IP_AR * NPIXP + ph], Ai = prm[IP_AI * NPIXP + ph];
    float Br = prm[IP_BR * NPIXP + ph], Bi = prm[IP_BI * NPIXP + ph];
    float Pm = prm[IP_P * NPIXP + ph], Qm = prm[IP_Q * NPIXP + ph], Rm = prm[IP_R * NPIXP + ph];
    float c2t = prm[IP_C2T * NPIXP + ph], s2t = prm[IP_S2T * NPIXP + ph];
    float k = prm[IP_K * NPIXP + ph];
    float w_ = fmaf(xx, c2t, fmaf(yy, s2t, dc));
    float sw, cw;
    sincosf(k * w_, &sw, &cw);
    float rr = fmaf(cw, Ar, sw * Br);
    float ri = fmaf(cw, Ai, sw * Bi);
    float lhs = fmaf(cw * cw, Pm, fmaf(2.f * cw * sw, Qm, sw * sw * Rm));
    xr[v] = rr / lhs;
    xi[v] = sign * ri / lhs;
  }
  __syncthreads();
  int b = threadIdx.x;
  if (b < NP) {
    int xb = (b + 120) % NF;
    float stc, sts;
    sincosf(TWO_PI * (float)xb / (float)NF, &sts, &stc);
    float c = 1.f, s = 0.f, accR = 0.f, accI = 0.f;
    for (int vv = 0; vv < NF; ++vv) {
      float xrv = xr[vv], xiv = xi[vv];
      accR = fmaf(xrv, c, accR); accR = fmaf(-xiv, s, accR);
      accI = fmaf(xrv, s, accI); accI = fmaf(xiv, c, accI);
      rot(c, s, stc, sts);
    }
    G[(size_t)u * NP + b] = make_float2(accR, accI);
  }
}

// inverse pass 2: out[a][b] = Re(sum_u G[u][b] e^{+2pi i ya u/160})/25600
__global__ __launch_bounds__(64) void k_ifft_y(const float2* __restrict__ G,
                                               float* __restrict__ out) {
  int idx = blockIdx.x * 64 + threadIdx.x;    // 6400
  int b = idx % NP;
  int a = idx / NP;
  int ya = (a + 120) % NF;
  float stc, sts;
  sincosf(TWO_PI * (float)ya / (float)NF, &sts, &stc);
  float c = 1.f, s = 0.f, accR = 0.f;
  for (int u = 0; u < NF; ++u) {
    float2 g = G[(size_t)u * NP + b];
    accR = fmaf(g.x, c, accR);
    accR = fmaf(-g.y, s, accR);
    rot(c, s, stc, sts);
  }
  out[idx] = accR * (1.f / 25600.f);
}

extern "C" void kernel_launch(void* const* d_in, const int* in_sizes, int n_in,
                              void* d_out, int out_size, void* d_ws, size_t ws_size,
                              hipStream_t stream) {
  (void)in_sizes; (void)n_in; (void)out_size; (void)ws_size;
  const float* patch  = (const float*)d_in[0];
  const float* gw     = (const float*)d_in[1];
  const float* delays = (const float*)d_in[2];
  const float* theta  = (const float*)d_in[4];
  const float* kloss  = (const float*)d_in[5];
  const float* cand   = (const float*)d_in[6];
  float* out = (float*)d_out;

  char* ws = (char*)d_ws;
  size_t off = 0;
  float2* Y = (float2*)(ws + off);      off += (size_t)ND * NF * NV * 8;     // 6,635,520
  float2* T = (float2*)(ws + off);      off += (size_t)ND * NP * NV * 8;     // 3,317,760
  float2* Yk2 = (float2*)(ws + off);    off += (size_t)(ND / 2) * NPIXP * 8; // 3,342,336
  float* prm = (float*)(ws + off);      off += (size_t)NPRM * NPIXP * 4;     //   887,808
  float* partial = (float*)(ws + off);  off += (size_t)NJ * NC * 4;          //   104,448
  float2* G = (float2*)(ws + off);      off += (size_t)NF * NP * 8;          //   102,400
  int* bestIdx = (int*)(ws + off);

  hipLaunchKernelGGL(k_fft_x, dim3((ND * NP * NV) / 256), dim3(256), 0, stream, patch, gw, T);
  hipLaunchKernelGGL(k_fft_y, dim3((ND * 40 * NV) / 256), dim3(256), 0, stream, T, Y);
  hipLaunchKernelGGL(k_prep, dim3(NXBLK), dim3(256), 0, stream, Y, delays, kloss, theta, Yk2, prm);
  hipLaunchKernelGGL(k_cand, dim3(NXBLK, NC / CPB), dim3(256), 0, stream, Yk2, prm, cand, partial);
  hipLaunchKernelGGL(k_argmin, dim3(1), dim3(NC), 0, stream, partial, cand, out, bestIdx);
  hipLaunchKernelGGL(k_ifft_u, dim3(NF), dim3(256), 0, stream, prm, cand, bestIdx, G);
  hipLaunchKernelGGL(k_ifft_y, dim3(100), dim3(64), 0, stream, G, out);
}

// Round 4
// 100.520 us; speedup vs baseline: 1.2448x; 1.2448x over previous
//
#include <hip/hip_runtime.h>

#define NF 160
#define NP 80
#define ND 64
#define NC 512
#define NV 81                  // stored v columns 0..80 (Hermitian half)
#define NPIXH (NF*NV)          // 12960
#define NPIXP 13056            // padded to 51*256
#define NXBLK 51
#define NJ NXBLK               // partial rows = blocks (reduced in-block)
#define CPB 16                 // candidates per block
#define TWO_PI 6.283185307179586f

// per-pixel precomputed parameter slots
#define IP_AR 0
#define IP_AI 1
#define IP_BR 2
#define IP_BI 3
#define IP_P  4
#define IP_Q  5
#define IP_R  6
#define IP_C2T 7
#define IP_S2T 8
#define IP_K  9
#define IP_CD0 10
#define IP_SD0 11
#define IP_CD1 12
#define IP_SD1 13
#define IP_TCD 14
#define IP_S0 15
#define IP_W  16
#define NPRM 17

__device__ __forceinline__ void rot(float& c, float& s, float stc, float sts) {
  float t1 = s * sts;
  float t2 = s * stc;
  float cn = fmaf(c, stc, -t1);
  s = fmaf(c, sts, t2);
  c = cn;
}

__device__ __forceinline__ void start_i_pow(int n, float& c, float& s) {
  switch (n & 3) {
    case 0: c = 1.f; s = 0.f; break;
    case 1: c = 0.f; s = 1.f; break;
    case 2: c = -1.f; s = 0.f; break;
    default: c = 0.f; s = -1.f; break;
  }
}

// Pass 1: T[d][a][v] = sum_b yw[d,a,b] * e^{-2pi i v (b-40)/160}, v in 0..80
__global__ __launch_bounds__(256) void k_fft_x(const float* __restrict__ patch,
                                               const float* __restrict__ gw,
                                               float2* __restrict__ T) {
  int idx = blockIdx.x * 256 + threadIdx.x;   // ND*NP*NV = 414720
  int v = idx % NV;
  int a = (idx / NV) % NP;
  int d = idx / (NV * NP);
  float c, s;
  start_i_pow(v, c, s);
  float stc, sts;
  sincosf(-TWO_PI * (float)v / (float)NF, &sts, &stc);
  const float* prow = patch + (size_t)(d * NP + a) * NP;
  const float* grow = gw + a * NP;
  float accR = 0.f, accI = 0.f;
  for (int b = 0; b < NP; ++b) {
    float f = prow[b] * grow[b];
    accR = fmaf(f, c, accR);
    accI = fmaf(f, s, accI);
    rot(c, s, stc, sts);
  }
  T[idx] = make_float2(accR, accI);
}

// Pass 2: Y[d][u][v] = sum_a T[d][a][v] * e^{-2pi i u (a-40)/160}
__global__ __launch_bounds__(256) void k_fft_y(const float2* __restrict__ T,
                                               float2* __restrict__ Y) {
  int idx = blockIdx.x * 256 + threadIdx.x;   // 64*40*81 = 207360
  int v = idx % NV;
  int ug = (idx / NV) % 40;
  int d = idx / (NV * 40);
  float c[4], s[4], aR[4], aI[4], stc[4], sts[4];
#pragma unroll
  for (int j = 0; j < 4; ++j) {
    int u = ug * 4 + j;
    start_i_pow(u, c[j], s[j]);
    sincosf(-TWO_PI * (float)u / (float)NF, &sts[j], &stc[j]);
    aR[j] = 0.f; aI[j] = 0.f;
  }
  const float2* Tb = T + (size_t)(d * NP) * NV + v;
  for (int a = 0; a < NP; ++a) {
    float2 t = Tb[(size_t)a * NV];
#pragma unroll
    for (int j = 0; j < 4; ++j) {
      aR[j] = fmaf(t.x, c[j], aR[j]);
      aR[j] = fmaf(-t.y, s[j], aR[j]);
      aI[j] = fmaf(t.x, s[j], aI[j]);
      aI[j] = fmaf(t.y, c[j], aI[j]);
      rot(c[j], s[j], stc[j], sts[j]);
    }
  }
#pragma unroll
  for (int j = 0; j < 4; ++j) {
    int u = ug * 4 + j;
    Y[((size_t)d * NF + u) * NV + v] = make_float2(aR[j], aI[j]);
  }
}

// Per-pixel candidate-independent moments over half-plane (padded).
// Yk4[jj][p] = (yk[2jj], yk[63-2jj], yk[2jj+1], yk[62-2jj])
__global__ __launch_bounds__(256) void k_prep(const float2* __restrict__ Y,
                                              const float* __restrict__ delays,
                                              const float* __restrict__ kloss,
                                              const float* __restrict__ theta,
                                              float4* __restrict__ Yk4,
                                              float* __restrict__ prm) {
  int p = blockIdx.x * 256 + threadIdx.x;     // 51*256 = 13056
  if (p >= NPIXH) {
#pragma unroll
    for (int jj = 0; jj < ND / 4; ++jj)
      Yk4[(size_t)jj * NPIXP + p] = make_float4(0.f, 0.f, 0.f, 0.f);
    prm[IP_AR * NPIXP + p] = 0.f;  prm[IP_AI * NPIXP + p] = 0.f;
    prm[IP_BR * NPIXP + p] = 0.f;  prm[IP_BI * NPIXP + p] = 0.f;
    prm[IP_P * NPIXP + p] = 1.f;   prm[IP_Q * NPIXP + p] = 0.f;
    prm[IP_R * NPIXP + p] = 1.f;   prm[IP_C2T * NPIXP + p] = 0.f;
    prm[IP_S2T * NPIXP + p] = 0.f; prm[IP_K * NPIXP + p] = 0.f;
    prm[IP_CD0 * NPIXP + p] = 1.f; prm[IP_SD0 * NPIXP + p] = 0.f;
    prm[IP_CD1 * NPIXP + p] = 1.f; prm[IP_SD1 * NPIXP + p] = 0.f;
    prm[IP_TCD * NPIXP + p] = 2.f; prm[IP_S0 * NPIXP + p] = 0.f;
    prm[IP_W * NPIXP + p] = 0.f;
    return;
  }
  int u = p / NV, v = p % NV;
  float k = kloss[u * NF + v];
  float th = theta[((u + 80) % NF) * NF + ((v + 80) % NF)];
  float c2t = cosf(2.f * th), s2t = sinf(2.f * th);
  float w;
  if (v == 0 || v == 80) {
    if (u == 0 || u == 80) w = 1.f;
    else if (u < 80) w = 2.f;
    else w = 0.f;
  } else w = 2.f;
  float d0 = delays[0], d1 = delays[1];
  float sd0f, cd0f;
  sincosf(k * d0, &sd0f, &cd0f);
  float stc, sts;
  sincosf(k * (d1 - d0), &sts, &stc);
  float tcd = 2.f * stc;
  float cd = cd0f, sd = sd0f;
  float cd1s = 0.f, sd1s = 0.f;
  float Ar = 0.f, Ai = 0.f, Br = 0.f, Bi = 0.f, Pm = 0.f, Qm = 0.f, Rm = 0.f, S0 = 0.f;
  float yktmp[ND];
#pragma unroll
  for (int d = 0; d < ND; ++d) {
    if (d == 1) { cd1s = cd; sd1s = sd; }
    float2 y = Y[((size_t)d * NF + u) * NV + v];
    Ar = fmaf(y.x, cd, Ar);  Ai = fmaf(y.y, cd, Ai);
    Br = fmaf(y.x, sd, Br);  Bi = fmaf(y.y, sd, Bi);
    Pm = fmaf(cd, cd, Pm);  Qm = fmaf(cd, sd, Qm);  Rm = fmaf(sd, sd, Rm);
    float yk = sqrtf(fmaf(y.x, y.x, y.y * y.y)) * k;
    yktmp[d] = yk;
    S0 = fmaf(yk, yk, S0);
    rot(cd, sd, stc, sts);
  }
#pragma unroll
  for (int jj = 0; jj < ND / 4; ++jj)
    Yk4[(size_t)jj * NPIXP + p] = make_float4(yktmp[2 * jj], yktmp[63 - 2 * jj],
                                              yktmp[2 * jj + 1], yktmp[62 - 2 * jj]);
  prm[IP_AR * NPIXP + p] = Ar;   prm[IP_AI * NPIXP + p] = Ai;
  prm[IP_BR * NPIXP + p] = Br;   prm[IP_BI * NPIXP + p] = Bi;
  prm[IP_P * NPIXP + p] = Pm;    prm[IP_Q * NPIXP + p] = Qm;
  prm[IP_R * NPIXP + p] = Rm;    prm[IP_C2T * NPIXP + p] = c2t;
  prm[IP_S2T * NPIXP + p] = s2t; prm[IP_K * NPIXP + p] = k;
  prm[IP_CD0 * NPIXP + p] = cd0f; prm[IP_SD0 * NPIXP + p] = sd0f;
  prm[IP_CD1 * NPIXP + p] = cd1s; prm[IP_SD1 * NPIXP + p] = sd1s;
  prm[IP_TCD * NPIXP + p] = tcd; prm[IP_S0 * NPIXP + p] = S0;
  prm[IP_W * NPIXP + p] = w;
}

// Hot kernel: per (pixel, candidate) loss via dual Chebyshev chains.
// yk pinned in VGPRs via opaque asm (prevents compiler sinking loads into loop).
__global__ __launch_bounds__(256, 3) void k_cand(const float4* __restrict__ Yk4,
                                                 const float* __restrict__ prm,
                                                 const float* __restrict__ cand,
                                                 float* __restrict__ partial) {
  int p = blockIdx.x * 256 + threadIdx.x;     // NXBLK=51 blocks in x
  int c0 = blockIdx.y * CPB;
  float Ar = prm[IP_AR * NPIXP + p], Ai = prm[IP_AI * NPIXP + p];
  float Br = prm[IP_BR * NPIXP + p], Bi = prm[IP_BI * NPIXP + p];
  float Pm = prm[IP_P * NPIXP + p], Qm = prm[IP_Q * NPIXP + p], Rm = prm[IP_R * NPIXP + p];
  float c2t = prm[IP_C2T * NPIXP + p], s2t = prm[IP_S2T * NPIXP + p];
  float k = prm[IP_K * NPIXP + p];
  float cd0 = prm[IP_CD0 * NPIXP + p], sd0 = prm[IP_SD0 * NPIXP + p];
  float cd1 = prm[IP_CD1 * NPIXP + p], sd1 = prm[IP_SD1 * NPIXP + p];
  float tcd = prm[IP_TCD * NPIXP + p], S0 = prm[IP_S0 * NPIXP + p];
  float wgt = prm[IP_W * NPIXP + p];
  float4 yk[ND / 4];
#pragma unroll
  for (int jj = 0; jj < ND / 4; ++jj) yk[jj] = Yk4[(size_t)jj * NPIXP + p];
#pragma unroll
  for (int jj = 0; jj < ND / 4; ++jj)
    asm volatile("" : "+v"(yk[jj].x), "+v"(yk[jj].y), "+v"(yk[jj].z), "+v"(yk[jj].w));
  int wid = threadIdx.x >> 6;
  int lane = threadIdx.x & 63;
  __shared__ float sdata[CPB][4];
  for (int ci = 0; ci < CPB; ++ci) {
    int c = c0 + ci;
    float dc = cand[c * 3 + 0], xx = cand[c * 3 + 1], yy = cand[c * 3 + 2];
    float w_ = fmaf(xx, c2t, fmaf(yy, s2t, dc));
    float kw = k * w_;
    float sw, cw;
    __sincosf(kw, &sw, &cw);
    float rr = fmaf(cw, Ar, sw * Br);
    float ri = fmaf(cw, Ai, sw * Bi);
    float lhs = fmaf(cw * cw, Pm, fmaf(2.f * cw * sw, Qm, sw * sw * Rm));
    float rabs = __builtin_amdgcn_sqrtf(fmaf(rr, rr, ri * ri));
    float rl = __builtin_amdgcn_rcpf(lhs);
    float e = fmaf(-lhs, rl, 1.f);
    rl = fmaf(rl, e, rl);                     // refined 1/lhs
    float kX = k * rabs * rl;
    // chain inits: cos(a -/+ b) = ca*cb +/- sa*sb
    float t0 = cd0 * cw, u0 = sd0 * sw;
    float t1 = cd1 * cw, u1 = sd1 * sw;
    float Am1 = t0 + u0, Bm1 = t0 - u0;       // A_0, B_0
    float Ac  = t1 + u1, Bc  = t1 - u1;       // A_1, B_1
    float MA0 = yk[0].x * fabsf(Am1);
    float MB0 = yk[0].y * fabsf(Bm1);
    float MA1 = yk[0].z * fabsf(Ac);
    float MB1 = yk[0].w * fabsf(Bc);
#pragma unroll
    for (int jj = 1; jj < ND / 4; ++jj) {
      float An = fmaf(tcd, Ac, -Am1);
      float Bn = fmaf(tcd, Bc, -Bm1);
      MA0 = fmaf(yk[jj].x, fabsf(An), MA0);
      MB0 = fmaf(yk[jj].y, fabsf(Bn), MB0);
      float An2 = fmaf(tcd, An, -Ac);
      float Bn2 = fmaf(tcd, Bn, -Bc);
      MA1 = fmaf(yk[jj].z, fabsf(An2), MA1);
      MB1 = fmaf(yk[jj].w, fabsf(Bn2), MB1);
      Am1 = An; Ac = An2;
      Bm1 = Bn; Bc = Bn2;
    }
    float M = (MA0 + MA1) + (MB0 + MB1);
    float contrib = fmaf(kX * kX, lhs, fmaf(-2.f * kX, M, S0)) * wgt;
    for (int off = 32; off > 0; off >>= 1) contrib += __shfl_xor(contrib, off);
    if (lane == 0) sdata[ci][wid] = contrib;
  }
  __syncthreads();
  if (threadIdx.x < CPB) {
    int ci = threadIdx.x;
    float s = (sdata[ci][0] + sdata[ci][1]) + (sdata[ci][2] + sdata[ci][3]);
    partial[(size_t)blockIdx.x * NC + c0 + ci] = s;
  }
}

__global__ void k_argmin(const float* __restrict__ partial,
                         const float* __restrict__ cand,
                         float* __restrict__ out, int* __restrict__ bestIdx) {
  __shared__ float sl[NC];
  __shared__ int si[NC];
  int c = threadIdx.x;                        // 512 threads
  float s = 0.f;
#pragma unroll
  for (int j = 0; j < NJ; ++j) s += partial[(size_t)j * NC + c];
  sl[c] = s * (1.f / 1638400.f);
  si[c] = c;
  __syncthreads();
  for (int off = 256; off > 0; off >>= 1) {
    if (c < off) {
      float l2 = sl[c + off]; int i2 = si[c + off];
      if (l2 < sl[c] || (l2 == sl[c] && i2 < si[c])) { sl[c] = l2; si[c] = i2; }
    }
    __syncthreads();
  }
  if (c == 0) {
    int bi = si[0];
    out[6400] = cand[bi * 3 + 0];
    out[6401] = cand[bi * 3 + 1];
    out[6402] = cand[bi * 3 + 2];
    out[6403] = sl[0];
    *bestIdx = bi;
  }
}

// Fused: expand best X (Hermitian) for row u into LDS, then row-DFT:
// G[u][b] = sum_v X[u,v] e^{+2pi i xb v/160}, xb=(b+120)%160
__global__ __launch_bounds__(256) void k_ifft_u(const float* __restrict__ prm,
                                                const float* __restrict__ cand,
                                                const int* __restrict__ bestIdx,
                                                float2* __restrict__ G) {
  int u = blockIdx.x;                         // 0..159
  __shared__ float xr[NF], xi[NF];
  int bi = *bestIdx;
  float dc = cand[bi * 3 + 0], xx = cand[bi * 3 + 1], yy = cand[bi * 3 + 2];
  int v = threadIdx.x;
  if (v < NF) {
    float sign = 1.f;
    int ph;
    if (v <= 80) {
      ph = u * NV + v;
    } else {
      int u2 = (NF - u) % NF;
      ph = u2 * NV + (NF - v);
      sign = -1.f;
    }
    float Ar = prm[IP_AR * NPIXP + ph], Ai = prm[IP_AI * NPIXP + ph];
    float Br = prm[IP_BR * NPIXP + ph], Bi = prm[IP_BI * NPIXP + ph];
    float Pm = prm[IP_P * NPIXP + ph], Qm = prm[IP_Q * NPIXP + ph], Rm = prm[IP_R * NPIXP + ph];
    float c2t = prm[IP_C2T * NPIXP + ph], s2t = prm[IP_S2T * NPIXP + ph];
    float k = prm[IP_K * NPIXP + ph];
    float w_ = fmaf(xx, c2t, fmaf(yy, s2t, dc));
    float sw, cw;
    sincosf(k * w_, &sw, &cw);
    float rr = fmaf(cw, Ar, sw * Br);
    float ri = fmaf(cw, Ai, sw * Bi);
    float lhs = fmaf(cw * cw, Pm, fmaf(2.f * cw * sw, Qm, sw * sw * Rm));
    xr[v] = rr / lhs;
    xi[v] = sign * ri / lhs;
  }
  __syncthreads();
  int b = threadIdx.x;
  if (b < NP) {
    int xb = (b + 120) % NF;
    float stc, sts;
    sincosf(TWO_PI * (float)xb / (float)NF, &sts, &stc);
    float c = 1.f, s = 0.f, accR = 0.f, accI = 0.f;
    for (int vv = 0; vv < NF; ++vv) {
      float xrv = xr[vv], xiv = xi[vv];
      accR = fmaf(xrv, c, accR); accR = fmaf(-xiv, s, accR);
      accI = fmaf(xrv, s, accI); accI = fmaf(xiv, c, accI);
      rot(c, s, stc, sts);
    }
    G[(size_t)u * NP + b] = make_float2(accR, accI);
  }
}

// inverse pass 2: out[a][b] = Re(sum_u G[u][b] e^{+2pi i ya u/160})/25600
__global__ __launch_bounds__(64) void k_ifft_y(const float2* __restrict__ G,
                                               float* __restrict__ out) {
  int idx = blockIdx.x * 64 + threadIdx.x;    // 6400
  int b = idx % NP;
  int a = idx / NP;
  int ya = (a + 120) % NF;
  float stc, sts;
  sincosf(TWO_PI * (float)ya / (float)NF, &sts, &stc);
  float c = 1.f, s = 0.f, accR = 0.f;
  for (int u = 0; u < NF; ++u) {
    float2 g = G[(size_t)u * NP + b];
    accR = fmaf(g.x, c, accR);
    accR = fmaf(-g.y, s, accR);
    rot(c, s, stc, sts);
  }
  out[idx] = accR * (1.f / 25600.f);
}

extern "C" void kernel_launch(void* const* d_in, const int* in_sizes, int n_in,
                              void* d_out, int out_size, void* d_ws, size_t ws_size,
                              hipStream_t stream) {
  (void)in_sizes; (void)n_in; (void)out_size; (void)ws_size;
  const float* patch  = (const float*)d_in[0];
  const float* gw     = (const float*)d_in[1];
  const float* delays = (const float*)d_in[2];
  const float* theta  = (const float*)d_in[4];
  const float* kloss  = (const float*)d_in[5];
  const float* cand   = (const float*)d_in[6];
  float* out = (float*)d_out;

  char* ws = (char*)d_ws;
  size_t off = 0;
  float2* Y = (float2*)(ws + off);      off += (size_t)ND * NF * NV * 8;     // 6,635,520
  float2* T = (float2*)(ws + off);      off += (size_t)ND * NP * NV * 8;     // 3,317,760
  float4* Yk4 = (float4*)(ws + off);    off += (size_t)(ND / 4) * NPIXP * 16;// 3,342,336
  float* prm = (float*)(ws + off);      off += (size_t)NPRM * NPIXP * 4;     //   887,808
  float* partial = (float*)(ws + off);  off += (size_t)NJ * NC * 4;          //   104,448
  float2* G = (float2*)(ws + off);      off += (size_t)NF * NP * 8;          //   102,400
  int* bestIdx = (int*)(ws + off);

  hipLaunchKernelGGL(k_fft_x, dim3((ND * NP * NV) / 256), dim3(256), 0, stream, patch, gw, T);
  hipLaunchKernelGGL(k_fft_y, dim3((ND * 40 * NV) / 256), dim3(256), 0, stream, T, Y);
  hipLaunchKernelGGL(k_prep, dim3(NXBLK), dim3(256), 0, stream, Y, delays, kloss, theta, Yk4, prm);
  hipLaunchKernelGGL(k_cand, dim3(NXBLK, NC / CPB), dim3(256), 0, stream, Yk4, prm, cand, partial);
  hipLaunchKernelGGL(k_argmin, dim3(1), dim3(NC), 0, stream, partial, cand, out, bestIdx);
  hipLaunchKernelGGL(k_ifft_u, dim3(NF), dim3(256), 0, stream, prm, cand, bestIdx, G);
  hipLaunchKernelGGL(k_ifft_y, dim3(100), dim3(64), 0, stream, G, out);
}